// Round 1
// baseline (349.917 us; speedup 1.0000x reference)
//
#include <hip/hip_runtime.h>
#include <stdint.h>

// GlobalAddAttention: B=64 graphs, L=256 (1 metal + 255 nodes), E=512, H=8, Dh=64
// Pipeline: pack(bf16) -> QKV GEMM (MFMA) -> attention (MFMA, full-S) -> out GEMM (MFMA)

#define EMB    512
#define NH     8
#define NGR    64
#define SEQL   256
#define DHEAD  64
#define MROWS  16384   // NGR*SEQL

typedef __attribute__((ext_vector_type(4))) float f32x4;
typedef __attribute__((ext_vector_type(4))) short s16x4;
typedef __attribute__((ext_vector_type(8))) short s16x8;

__device__ __forceinline__ short f2bf(float f) {
  uint32_t u = __builtin_bit_cast(uint32_t, f);
  u += 0x7FFFu + ((u >> 16) & 1u);           // round-to-nearest-even
  return (short)(u >> 16);
}

__device__ __forceinline__ f32x4 mfma16(s16x8 a, s16x8 b, f32x4 c) {
  return __builtin_amdgcn_mfma_f32_16x16x32_bf16(a, b, c, 0, 0, 0);
}

__device__ __forceinline__ void gload_lds16(const void* g, void* l) {
  __builtin_amdgcn_global_load_lds(
      (const __attribute__((address_space(1))) void*)g,
      (__attribute__((address_space(3))) void*)l, 16, 0, 0);
}

// ---------------------------------------------------------------- pack kernels

// value[b*256+l][e] = (l==0) ? metal_x[b][e] : x[b*255+l-1][e], as bf16
__global__ void pack_value(const float* __restrict__ x, const float* __restrict__ mx,
                           short* __restrict__ val) {
  int gid = blockIdx.x * 256 + threadIdx.x;       // 2,097,152 threads, 4 elems each
  int i = gid << 2;
  int row = i >> 9, col = i & 511;
  int b = row >> 8, l = row & 255;
  const float* src = l ? x  + ((size_t)(b * 255 + l - 1) << 9) + col
                       : mx + ((size_t)b << 9) + col;
  f32x4 f = *(const f32x4*)src;
  s16x4 o = { f2bf(f[0]), f2bf(f[1]), f2bf(f[2]), f2bf(f[3]) };
  *(s16x4*)(val + i) = o;
}

// wqkv[(which*512+o)*512+k] bf16 (which: 0=q,1=k,2=v); wo bf16; bias_qkv fp32 concat
__global__ void pack_w(const float* __restrict__ Wq, const float* __restrict__ Wk,
                       const float* __restrict__ Wv, const float* __restrict__ Wo,
                       const float* __restrict__ bq, const float* __restrict__ bk,
                       const float* __restrict__ bv,
                       short* __restrict__ wqkv, short* __restrict__ wo,
                       float* __restrict__ bias_qkv) {
  int gid = blockIdx.x * 256 + threadIdx.x;       // 262,144 threads
  int i = gid << 2;
  const float* src; short* dst;
  if (i < 786432) {
    int which = i >> 18, off = i & 262143;
    src = (which == 0 ? Wq : which == 1 ? Wk : Wv) + off;
    dst = wqkv + i;
  } else {
    int off = i - 786432;
    src = Wo + off; dst = wo + off;
  }
  f32x4 f = *(const f32x4*)src;
  s16x4 o = { f2bf(f[0]), f2bf(f[1]), f2bf(f[2]), f2bf(f[3]) };
  *(s16x4*)dst = o;
  if (gid < 1536)
    bias_qkv[gid] = gid < 512 ? bq[gid] : gid < 1024 ? bk[gid - 512] : bv[gid - 1024];
}

// ------------------------------------------------------------------- GEMM
// C[M=16384, N] = A[M,512](bf16) @ Bt[N,512]^T + bias, m97 structure:
// 128x128 tile, BK=32, 4 waves (2x2), 4x4 16x16x32 frags per wave,
// global_load_lds width-16 staging, 2 barriers per K-step.
// mode 0: scatter q/k/v [B,H,L,64] bf16.  mode 1: scatter final fp32 output.
#define BM 128
#define BN 128
#define BK 32

__global__ __launch_bounds__(256, 2) void gemm_bt(
    const short* __restrict__ A, const short* __restrict__ Bt,
    const float* __restrict__ bias, int mode,
    short* __restrict__ qb, short* __restrict__ kb, short* __restrict__ vb,
    float* __restrict__ outp) {
  __shared__ short As[BM * BK];
  __shared__ short Bs[BN * BK];
  const int tid = threadIdx.x;
  const int lane = tid & 63, wid = tid >> 6;
  const int wr = wid >> 1, wc = wid & 1;
  const int l15 = lane & 15, l4 = lane >> 4;
  const int bm = blockIdx.x * BM, bn = blockIdx.y * BN;

  f32x4 acc[4][4];
#pragma unroll
  for (int r = 0; r < 4; ++r)
#pragma unroll
    for (int c = 0; c < 4; ++c) acc[r][c] = (f32x4){0.f, 0.f, 0.f, 0.f};

  for (int t = 0; t < 512 / BK; ++t) {
    __syncthreads();                 // previous compute done reading LDS
    const int bk = t * BK;
#pragma unroll
    for (int i = 0; i < 2; ++i) {
      int c = i * 256 + tid;
      int row = c >> 2, cc = (c & 3) * 8;
      gload_lds16(A + (size_t)(bm + row) * 512 + bk + cc, As + c * 8);
    }
#pragma unroll
    for (int i = 0; i < 2; ++i) {
      int c = i * 256 + tid;
      int row = c >> 2, cc = (c & 3) * 8;
      gload_lds16(Bt + (size_t)(bn + row) * 512 + bk + cc, Bs + c * 8);
    }
    __syncthreads();                 // drains vmcnt(0): staging complete

    s16x8 af[4], bf[4];
#pragma unroll
    for (int r = 0; r < 4; ++r)
      af[r] = *(const s16x8*)(As + (wr * 64 + r * 16 + l15) * BK + l4 * 8);
#pragma unroll
    for (int c = 0; c < 4; ++c)
      bf[c] = *(const s16x8*)(Bs + (wc * 64 + c * 16 + l15) * BK + l4 * 8);
#pragma unroll
    for (int r = 0; r < 4; ++r)
#pragma unroll
      for (int c = 0; c < 4; ++c)
        acc[r][c] = mfma16(af[r], bf[c], acc[r][c]);
  }

  // epilogue: D layout col = lane&15, row = (lane>>4)*4 + reg  [m89-verified]
#pragma unroll
  for (int r = 0; r < 4; ++r) {
    int row0 = bm + wr * 64 + r * 16 + l4 * 4;
#pragma unroll
    for (int c = 0; c < 4; ++c) {
      int col_g = bn + wc * 64 + c * 16 + l15;
      float bvv = bias[col_g];
#pragma unroll
      for (int j = 0; j < 4; ++j) {
        float v = acc[r][c][j] + bvv;
        int row = row0 + j;
        int b = row >> 8, lrow = row & 255;
        if (mode == 0) {
          int which = col_g >> 9, rem = col_g & 511;
          int h = rem >> 6, dh = rem & 63;
          size_t idx = ((size_t)((b * 8 + h) * 256 + lrow)) * 64 + dh;
          (which == 0 ? qb : which == 1 ? kb : vb)[idx] = f2bf(v);
        } else {
          // out_lb is [L,B,E]: l==0 -> metal block, else ((l-1)*64+b)*512+e
          size_t idx = (lrow == 0)
                         ? (size_t)16320 * 512 + (size_t)b * 512 + col_g
                         : ((size_t)(lrow - 1) * 64 + b) * 512 + col_g;
          outp[idx] = v;
        }
      }
    }
  }
}

// ---------------------------------------------------------------- attention
// grid = 1024 blocks: blockIdx -> (bh = b*8+h, half). 256 thr = 4 waves,
// each wave owns 32 query rows. Full S (32x256 fp32) in registers,
// two-pass softmax (no online rescale). K B-frags straight from global (L2).
// V transposed into XOR-swizzled LDS; P staged per-wave in padded LDS.
#define VT_ROWB 544   // 272 bf16 per row (256 keys + pad), 16B aligned

__global__ __launch_bounds__(256, 2) void attn(
    const short* __restrict__ qb, const short* __restrict__ kb,
    const short* __restrict__ vb, short* __restrict__ attn_out) {
  __shared__ short VT[64 * 272];        // [d][key] swizzled, 34816 B
  __shared__ short Pl[4][32 * 72];      // per-wave P chunk, 18432 B

  const int tid = threadIdx.x;
  const int lane = tid & 63, w = tid >> 6;
  const int l15 = lane & 15, l4 = lane >> 4;
  const int bh = blockIdx.x >> 1;
  const int qhalf = (blockIdx.x & 1) * 128;
  const size_t base = (size_t)bh * SEQL * DHEAD;

  // --- V -> VT[d][key] (bf16, XOR-swizzled so both write & b128 read are clean)
  {
    int d0 = (tid & 7) * 8;
    int krow = tid >> 3;                // 0..31
#pragma unroll
    for (int step = 0; step < 8; ++step) {
      int key = step * 32 + krow;
      s16x8 vv = *(const s16x8*)(vb + base + (size_t)key * 64 + d0);
#pragma unroll
      for (int j = 0; j < 8; ++j) {
        int d = d0 + j;
        int off = d * VT_ROWB + ((key * 2) ^ ((d << 1) & 0x70));
        *(short*)((char*)VT + off) = vv[j];
      }
    }
  }

  // --- Q A-frags (2 row-tiles x 2 k-slices)
  const int q0 = qhalf + w * 32;
  s16x8 qf[2][2];
#pragma unroll
  for (int rt = 0; rt < 2; ++rt)
#pragma unroll
    for (int kk = 0; kk < 2; ++kk)
      qf[rt][kk] = *(const s16x8*)(qb + base + (size_t)(q0 + rt * 16 + l15) * 64
                                   + kk * 32 + l4 * 8);

  __syncthreads();                      // VT ready for all waves

  // --- S = Q K^T  (per wave: 32 queries x 256 keys)
  f32x4 s[2][16];
#pragma unroll
  for (int rt = 0; rt < 2; ++rt)
#pragma unroll
    for (int ct = 0; ct < 16; ++ct) s[rt][ct] = (f32x4){0.f, 0.f, 0.f, 0.f};

#pragma unroll 4
  for (int ct = 0; ct < 16; ++ct) {
    const short* kp = kb + base + (size_t)(ct * 16 + l15) * 64 + l4 * 8;
    s16x8 kf0 = *(const s16x8*)(kp);
    s16x8 kf1 = *(const s16x8*)(kp + 32);
#pragma unroll
    for (int rt = 0; rt < 2; ++rt) {
      s[rt][ct] = mfma16(qf[rt][0], kf0, s[rt][ct]);
      s[rt][ct] = mfma16(qf[rt][1], kf1, s[rt][ct]);
    }
  }

  // --- softmax (rows live in (lane>>4)*4+reg; reduce over 16 key-lanes)
  const float scale = 0.125f;           // 1/sqrt(64)
  float lsum[2][4];
#pragma unroll
  for (int rt = 0; rt < 2; ++rt)
#pragma unroll
    for (int j = 0; j < 4; ++j) {
      float m = -1e30f;
#pragma unroll
      for (int ct = 0; ct < 16; ++ct) m = fmaxf(m, s[rt][ct][j]);
#pragma unroll
      for (int d = 1; d < 16; d <<= 1) m = fmaxf(m, __shfl_xor(m, d, 64));
      m *= scale;
      float ls = 0.f;
#pragma unroll
      for (int ct = 0; ct < 16; ++ct) {
        float p = __expf(s[rt][ct][j] * scale - m);
        s[rt][ct][j] = p;
        ls += p;
      }
#pragma unroll
      for (int d = 1; d < 16; d <<= 1) ls += __shfl_xor(ls, d, 64);
      lsum[rt][j] = ls;
    }

  // --- O = P V  (chunked: stage P 64 keys at a time in per-wave LDS)
  f32x4 o[2][4];
#pragma unroll
  for (int rt = 0; rt < 2; ++rt)
#pragma unroll
    for (int jt = 0; jt < 4; ++jt) o[rt][jt] = (f32x4){0.f, 0.f, 0.f, 0.f};

  for (int ck = 0; ck < 4; ++ck) {
#pragma unroll
    for (int rt = 0; rt < 2; ++rt)
#pragma unroll
      for (int c2 = 0; c2 < 4; ++c2)
#pragma unroll
        for (int j = 0; j < 4; ++j) {
          int q = rt * 16 + l4 * 4 + j;
          int col = c2 * 16 + l15;
          Pl[w][q * 72 + col] = f2bf(s[rt][ck * 4 + c2][j]);
        }
    // per-wave LDS: no barrier needed; compiler inserts lgkmcnt waits
#pragma unroll
    for (int kk = 0; kk < 2; ++kk) {
      s16x8 pf[2];
#pragma unroll
      for (int rt = 0; rt < 2; ++rt)
        pf[rt] = *(const s16x8*)(&Pl[w][(rt * 16 + l15) * 72 + kk * 32 + l4 * 8]);
#pragma unroll
      for (int jt = 0; jt < 4; ++jt) {
        int d = jt * 16 + l15;
        int k0 = ck * 64 + kk * 32 + l4 * 8;
        int off = d * VT_ROWB + ((k0 * 2) ^ ((d << 1) & 0x70));
        s16x8 vf = *(const s16x8*)((const char*)VT + off);
#pragma unroll
        for (int rt = 0; rt < 2; ++rt)
          o[rt][jt] = mfma16(pf[rt], vf, o[rt][jt]);
      }
    }
  }

  // --- normalize + store as bf16 A-matrix for the out-projection
  const int b = bh >> 3, h = bh & 7;
#pragma unroll
  for (int rt = 0; rt < 2; ++rt)
#pragma unroll
    for (int jt = 0; jt < 4; ++jt)
#pragma unroll
      for (int j = 0; j < 4; ++j) {
        float val = o[rt][jt][j] / lsum[rt][j];
        int qrow = q0 + rt * 16 + l4 * 4 + j;
        int d = jt * 16 + l15;
        attn_out[(size_t)(b * 256 + qrow) * 512 + h * 64 + d] = f2bf(val);
      }
}

// ---------------------------------------------------------------- launch

extern "C" void kernel_launch(void* const* d_in, const int* in_sizes, int n_in,
                              void* d_out, int out_size, void* d_ws, size_t ws_size,
                              hipStream_t stream) {
  (void)in_sizes; (void)n_in; (void)out_size; (void)ws_size;
  const float* x  = (const float*)d_in[0];
  const float* mx = (const float*)d_in[1];
  // d_in[2] = batch indices (structure known statically; unused)
  const float* Wq = (const float*)d_in[3];
  const float* Wk = (const float*)d_in[4];
  const float* Wv = (const float*)d_in[5];
  const float* bq = (const float*)d_in[6];
  const float* bk = (const float*)d_in[7];
  const float* bv = (const float*)d_in[8];
  const float* Wo = (const float*)d_in[9];
  const float* bo = (const float*)d_in[10];
  float* out = (float*)d_out;

  char* ws = (char*)d_ws;
  short* value = (short*)(ws);                    // 16,777,216 B
  short* wqkv  = (short*)(ws + 16777216);         //  1,572,864 B
  short* wo    = (short*)(ws + 18350080);         //    524,288 B
  float* biasq = (float*)(ws + 18874368);         //      6,144 B
  short* qbuf  = (short*)(ws + 18880512);         // 16,777,216 B
  short* kbuf  = (short*)(ws + 35657728);         // 16,777,216 B
  short* vbuf  = (short*)(ws + 52434944);         // 16,777,216 B -> 69,212,160 total
  short* attn_o = value;                          // value dead after QKV GEMM

  pack_value<<<8192, 256, 0, stream>>>(x, mx, value);
  pack_w<<<1024, 256, 0, stream>>>(Wq, Wk, Wv, Wo, bq, bk, bv, wqkv, wo, biasq);
  gemm_bt<<<dim3(128, 12), 256, 0, stream>>>(value, wqkv, biasq, 0,
                                             qbuf, kbuf, vbuf, nullptr);
  attn<<<1024, 256, 0, stream>>>(qbuf, kbuf, vbuf, attn_o);
  gemm_bt<<<dim3(128, 4), 256, 0, stream>>>(attn_o, wo, bo, 1,
                                            nullptr, nullptr, nullptr, out);
}

// Round 4
// 198.582 us; speedup vs baseline: 1.7621x; 1.7621x over previous
//
#include <hip/hip_runtime.h>
#include <stdint.h>

// GlobalAddAttention: B=64 graphs, L=256 (1 metal + 255 nodes), E=512, H=8, Dh=64
// Pipeline: pack(bf16) -> QKV GEMM (MFMA) -> attention (MFMA, full-S) -> out GEMM (MFMA)

#define EMB    512
#define NH     8
#define NGR    64
#define SEQL   256
#define DHEAD  64
#define MROWS  16384   // NGR*SEQL

typedef __attribute__((ext_vector_type(4))) float f32x4;
typedef __attribute__((ext_vector_type(4))) short s16x4;
typedef __attribute__((ext_vector_type(8))) short s16x8;

__device__ __forceinline__ short f2bf(float f) {
  uint32_t u = __builtin_bit_cast(uint32_t, f);
  u += 0x7FFFu + ((u >> 16) & 1u);           // round-to-nearest-even
  return (short)(u >> 16);
}

__device__ __forceinline__ f32x4 mfma16(s16x8 a, s16x8 b, f32x4 c) {
  return __builtin_amdgcn_mfma_f32_16x16x32_bf16(a, b, c, 0, 0, 0);
}

__device__ __forceinline__ void gload_lds16(const void* g, void* l) {
  __builtin_amdgcn_global_load_lds(
      (const __attribute__((address_space(1))) void*)g,
      (__attribute__((address_space(3))) void*)l, 16, 0, 0);
}

// ---------------------------------------------------------------- pack kernels

// value[b*256+l][e] = (l==0) ? metal_x[b][e] : x[b*255+l-1][e], as bf16
__global__ void pack_value(const float* __restrict__ x, const float* __restrict__ mx,
                           short* __restrict__ val) {
  int gid = blockIdx.x * 256 + threadIdx.x;       // 2,097,152 threads, 4 elems each
  int i = gid << 2;
  int row = i >> 9, col = i & 511;
  int b = row >> 8, l = row & 255;
  const float* src = l ? x  + ((size_t)(b * 255 + l - 1) << 9) + col
                       : mx + ((size_t)b << 9) + col;
  f32x4 f = *(const f32x4*)src;
  s16x4 o = { f2bf(f[0]), f2bf(f[1]), f2bf(f[2]), f2bf(f[3]) };
  *(s16x4*)(val + i) = o;
}

// wqkv[(which*512+o)*512+k] bf16 (which: 0=q,1=k,2=v); wo bf16; bias_qkv fp32 concat
__global__ void pack_w(const float* __restrict__ Wq, const float* __restrict__ Wk,
                       const float* __restrict__ Wv, const float* __restrict__ Wo,
                       const float* __restrict__ bq, const float* __restrict__ bk,
                       const float* __restrict__ bv,
                       short* __restrict__ wqkv, short* __restrict__ wo,
                       float* __restrict__ bias_qkv) {
  int gid = blockIdx.x * 256 + threadIdx.x;       // 262,144 threads
  int i = gid << 2;
  const float* src; short* dst;
  if (i < 786432) {
    int which = i >> 18, off = i & 262143;
    src = (which == 0 ? Wq : which == 1 ? Wk : Wv) + off;
    dst = wqkv + i;
  } else {
    int off = i - 786432;
    src = Wo + off; dst = wo + off;
  }
  f32x4 f = *(const f32x4*)src;
  s16x4 o = { f2bf(f[0]), f2bf(f[1]), f2bf(f[2]), f2bf(f[3]) };
  *(s16x4*)dst = o;
  if (gid < 1536)
    bias_qkv[gid] = gid < 512 ? bq[gid] : gid < 1024 ? bk[gid - 512] : bv[gid - 1024];
}

// ------------------------------------------------------------------- GEMM
// C[M=16384, N] = A[M,512](bf16) @ Bt[N,512]^T + bias, m97 structure:
// 128x128 tile, BK=32, 4 waves (2x2), 4x4 16x16x32 frags per wave,
// global_load_lds width-16 staging, 2 barriers per K-step.
// mode 0: scatter q/k/v [B,H,L,64] bf16.  mode 1: scatter final fp32 output.
#define BM 128
#define BN 128
#define BK 32

__global__ __launch_bounds__(256, 2) void gemm_bt(
    const short* __restrict__ A, const short* __restrict__ Bt,
    const float* __restrict__ bias, int mode,
    short* __restrict__ qb, short* __restrict__ kb, short* __restrict__ vb,
    float* __restrict__ outp) {
  __shared__ short As[BM * BK];
  __shared__ short Bs[BN * BK];
  const int tid = threadIdx.x;
  const int lane = tid & 63, wid = tid >> 6;
  const int wr = wid >> 1, wc = wid & 1;
  const int l15 = lane & 15, l4 = lane >> 4;
  const int bm = blockIdx.x * BM, bn = blockIdx.y * BN;

  f32x4 acc[4][4];
#pragma unroll
  for (int r = 0; r < 4; ++r)
#pragma unroll
    for (int c = 0; c < 4; ++c) acc[r][c] = (f32x4){0.f, 0.f, 0.f, 0.f};

  for (int t = 0; t < 512 / BK; ++t) {
    __syncthreads();                 // previous compute done reading LDS
    const int bk = t * BK;
#pragma unroll
    for (int i = 0; i < 2; ++i) {
      int c = i * 256 + tid;
      int row = c >> 2, cc = (c & 3) * 8;
      gload_lds16(A + (size_t)(bm + row) * 512 + bk + cc, As + c * 8);
    }
#pragma unroll
    for (int i = 0; i < 2; ++i) {
      int c = i * 256 + tid;
      int row = c >> 2, cc = (c & 3) * 8;
      gload_lds16(Bt + (size_t)(bn + row) * 512 + bk + cc, Bs + c * 8);
    }
    __syncthreads();                 // drains vmcnt(0): staging complete

    s16x8 af[4], bf[4];
#pragma unroll
    for (int r = 0; r < 4; ++r)
      af[r] = *(const s16x8*)(As + (wr * 64 + r * 16 + l15) * BK + l4 * 8);
#pragma unroll
    for (int c = 0; c < 4; ++c)
      bf[c] = *(const s16x8*)(Bs + (wc * 64 + c * 16 + l15) * BK + l4 * 8);
#pragma unroll
    for (int r = 0; r < 4; ++r)
#pragma unroll
      for (int c = 0; c < 4; ++c)
        acc[r][c] = mfma16(af[r], bf[c], acc[r][c]);
  }

  // epilogue: D layout col = lane&15, row = (lane>>4)*4 + reg  [m89-verified]
#pragma unroll
  for (int r = 0; r < 4; ++r) {
    int row0 = bm + wr * 64 + r * 16 + l4 * 4;
#pragma unroll
    for (int c = 0; c < 4; ++c) {
      int col_g = bn + wc * 64 + c * 16 + l15;
      float bvv = bias[col_g];
#pragma unroll
      for (int j = 0; j < 4; ++j) {
        float v = acc[r][c][j] + bvv;
        int row = row0 + j;
        int b = row >> 8, lrow = row & 255;
        if (mode == 0) {
          int which = col_g >> 9, rem = col_g & 511;
          int h = rem >> 6, dh = rem & 63;
          size_t idx = ((size_t)((b * 8 + h) * 256 + lrow)) * 64 + dh;
          (which == 0 ? qb : which == 1 ? kb : vb)[idx] = f2bf(v);
        } else {
          // out_lb is [L,B,E]: l==0 -> metal block, else ((l-1)*64+b)*512+e
          size_t idx = (lrow == 0)
                         ? (size_t)16320 * 512 + (size_t)b * 512 + col_g
                         : ((size_t)(lrow - 1) * 64 + b) * 512 + col_g;
          outp[idx] = v;
        }
      }
    }
  }
}

// ---------------------------------------------------------------- attention
// grid = 1024 blocks: blockIdx -> (bh = b*8+h, half). 256 thr = 4 waves,
// each wave owns 32 query rows. Full S (32x256 fp32) in registers,
// two-pass softmax (no online rescale). K B-frags straight from global (L2).
// V transposed into XOR-swizzled LDS; P staged per-wave in padded LDS.
// NOTE: every loop touching s[][] must be FULLY unrolled (rule #20) —
// partial unroll leaves a runtime index and pushes S (512 B/lane) to scratch.
#define VT_ROWB 544   // 272 bf16 per row (256 keys + pad), 16B aligned

__global__ __launch_bounds__(256, 2) void attn(
    const short* __restrict__ qb, const short* __restrict__ kb,
    const short* __restrict__ vb, short* __restrict__ attn_out) {
  __shared__ short VT[64 * 272];        // [d][key] swizzled, 34816 B
  __shared__ short Pl[4][32 * 72];      // per-wave P chunk, 18432 B

  const int tid = threadIdx.x;
  const int lane = tid & 63, w = tid >> 6;
  const int l15 = lane & 15, l4 = lane >> 4;
  const int bh = blockIdx.x >> 1;
  const int qhalf = (blockIdx.x & 1) * 128;
  const size_t base = (size_t)bh * SEQL * DHEAD;

  // --- V -> VT[d][key] (bf16, XOR-swizzled so both write & b128 read are clean)
  {
    int d0 = (tid & 7) * 8;
    int krow = tid >> 3;                // 0..31
#pragma unroll
    for (int step = 0; step < 8; ++step) {
      int key = step * 32 + krow;
      s16x8 vv = *(const s16x8*)(vb + base + (size_t)key * 64 + d0);
#pragma unroll
      for (int j = 0; j < 8; ++j) {
        int d = d0 + j;
        int off = d * VT_ROWB + ((key * 2) ^ ((d << 1) & 0x70));
        *(short*)((char*)VT + off) = vv[j];
      }
    }
  }

  // --- Q A-frags (2 row-tiles x 2 k-slices)
  const int q0 = qhalf + w * 32;
  s16x8 qf[2][2];
#pragma unroll
  for (int rt = 0; rt < 2; ++rt)
#pragma unroll
    for (int kk = 0; kk < 2; ++kk)
      qf[rt][kk] = *(const s16x8*)(qb + base + (size_t)(q0 + rt * 16 + l15) * 64
                                   + kk * 32 + l4 * 8);

  __syncthreads();                      // VT ready for all waves

  // --- S = Q K^T  (per wave: 32 queries x 256 keys)
  f32x4 s[2][16];
#pragma unroll
  for (int rt = 0; rt < 2; ++rt)
#pragma unroll
    for (int ct = 0; ct < 16; ++ct) s[rt][ct] = (f32x4){0.f, 0.f, 0.f, 0.f};

#pragma unroll                          // FULL unroll: ct must be compile-time
  for (int ct = 0; ct < 16; ++ct) {
    const short* kp = kb + base + (size_t)(ct * 16 + l15) * 64 + l4 * 8;
    s16x8 kf0 = *(const s16x8*)(kp);
    s16x8 kf1 = *(const s16x8*)(kp + 32);
#pragma unroll
    for (int rt = 0; rt < 2; ++rt) {
      s[rt][ct] = mfma16(qf[rt][0], kf0, s[rt][ct]);
      s[rt][ct] = mfma16(qf[rt][1], kf1, s[rt][ct]);
    }
  }

  // --- softmax (rows live in (lane>>4)*4+reg; reduce over 16 key-lanes)
  const float scale = 0.125f;           // 1/sqrt(64)
  float lsum[2][4];
#pragma unroll
  for (int rt = 0; rt < 2; ++rt)
#pragma unroll
    for (int j = 0; j < 4; ++j) {
      float m = -1e30f;
#pragma unroll
      for (int ct = 0; ct < 16; ++ct) m = fmaxf(m, s[rt][ct][j]);
#pragma unroll
      for (int d = 1; d < 16; d <<= 1) m = fmaxf(m, __shfl_xor(m, d, 64));
      m *= scale;
      float ls = 0.f;
#pragma unroll
      for (int ct = 0; ct < 16; ++ct) {
        float p = __expf(s[rt][ct][j] * scale - m);
        s[rt][ct][j] = p;
        ls += p;
      }
#pragma unroll
      for (int d = 1; d < 16; d <<= 1) ls += __shfl_xor(ls, d, 64);
      lsum[rt][j] = ls;
    }

  // --- O = P V  (chunked: stage P 64 keys at a time in per-wave LDS)
  f32x4 o[2][4];
#pragma unroll
  for (int rt = 0; rt < 2; ++rt)
#pragma unroll
    for (int jt = 0; jt < 4; ++jt) o[rt][jt] = (f32x4){0.f, 0.f, 0.f, 0.f};

#pragma unroll                          // FULL unroll: ck must be compile-time
  for (int ck = 0; ck < 4; ++ck) {
#pragma unroll
    for (int rt = 0; rt < 2; ++rt)
#pragma unroll
      for (int c2 = 0; c2 < 4; ++c2)
#pragma unroll
        for (int j = 0; j < 4; ++j) {
          int q = rt * 16 + l4 * 4 + j;
          int col = c2 * 16 + l15;
          Pl[w][q * 72 + col] = f2bf(s[rt][ck * 4 + c2][j]);
        }
    // per-wave LDS: no barrier needed; compiler inserts lgkmcnt waits
#pragma unroll
    for (int kk = 0; kk < 2; ++kk) {
      s16x8 pf[2];
#pragma unroll
      for (int rt = 0; rt < 2; ++rt)
        pf[rt] = *(const s16x8*)(&Pl[w][(rt * 16 + l15) * 72 + kk * 32 + l4 * 8]);
#pragma unroll
      for (int jt = 0; jt < 4; ++jt) {
        int d = jt * 16 + l15;
        int k0 = ck * 64 + kk * 32 + l4 * 8;
        int off = d * VT_ROWB + ((k0 * 2) ^ ((d << 1) & 0x70));
        s16x8 vf = *(const s16x8*)((const char*)VT + off);
#pragma unroll
        for (int rt = 0; rt < 2; ++rt)
          o[rt][jt] = mfma16(pf[rt], vf, o[rt][jt]);
      }
    }
  }

  // --- normalize + store as bf16 A-matrix for the out-projection
  const int b = bh >> 3, h = bh & 7;
#pragma unroll
  for (int rt = 0; rt < 2; ++rt)
#pragma unroll
    for (int jt = 0; jt < 4; ++jt)
#pragma unroll
      for (int j = 0; j < 4; ++j) {
        float val = o[rt][jt][j] / lsum[rt][j];
        int qrow = q0 + rt * 16 + l4 * 4 + j;
        int d = jt * 16 + l15;
        attn_out[(size_t)(b * 256 + qrow) * 512 + h * 64 + d] = f2bf(val);
      }
}

// ---------------------------------------------------------------- launch

extern "C" void kernel_launch(void* const* d_in, const int* in_sizes, int n_in,
                              void* d_out, int out_size, void* d_ws, size_t ws_size,
                              hipStream_t stream) {
  (void)in_sizes; (void)n_in; (void)out_size; (void)ws_size;
  const float* x  = (const float*)d_in[0];
  const float* mx = (const float*)d_in[1];
  // d_in[2] = batch indices (structure known statically; unused)
  const float* Wq = (const float*)d_in[3];
  const float* Wk = (const float*)d_in[4];
  const float* Wv = (const float*)d_in[5];
  const float* bq = (const float*)d_in[6];
  const float* bk = (const float*)d_in[7];
  const float* bv = (const float*)d_in[8];
  const float* Wo = (const float*)d_in[9];
  const float* bo = (const float*)d_in[10];
  float* out = (float*)d_out;

  char* ws = (char*)d_ws;
  short* value = (short*)(ws);                    // 16,777,216 B
  short* wqkv  = (short*)(ws + 16777216);         //  1,572,864 B
  short* wo    = (short*)(ws + 18350080);         //    524,288 B
  float* biasq = (float*)(ws + 18874368);         //      6,144 B
  short* qbuf  = (short*)(ws + 18880512);         // 16,777,216 B
  short* kbuf  = (short*)(ws + 35657728);         // 16,777,216 B
  short* vbuf  = (short*)(ws + 52434944);         // 16,777,216 B -> 69,212,160 total
  short* attn_o = value;                          // value dead after QKV GEMM

  pack_value<<<8192, 256, 0, stream>>>(x, mx, value);
  pack_w<<<1024, 256, 0, stream>>>(Wq, Wk, Wv, Wo, bq, bk, bv, wqkv, wo, biasq);
  gemm_bt<<<dim3(128, 12), 256, 0, stream>>>(value, wqkv, biasq, 0,
                                             qbuf, kbuf, vbuf, nullptr);
  attn<<<1024, 256, 0, stream>>>(qbuf, kbuf, vbuf, attn_o);
  gemm_bt<<<dim3(128, 4), 256, 0, stream>>>(attn_o, wo, bo, 1,
                                            nullptr, nullptr, nullptr, out);
}